// Round 13
// baseline (403.602 us; speedup 1.0000x reference)
//
#include <hip/hip_runtime.h>
#include <hip/hip_bf16.h>
#include <math.h>

#define N_NODES 10000
#define N_GRAPHS 64
#define N_EDGES 160000
#define D_INPUT 128
#define D_H 512
#define EPS 1e-7f
#define MAXV 10.0f
#define BN_EPS 1e-5f
#define M_PAD 10112       // 79 * 128
#define GEMM_BLOCKS 316   // 79 * 4

typedef __attribute__((ext_vector_type(4))) float f32x4;
typedef __attribute__((ext_vector_type(8))) __bf16 bf16x8;

// ================= fused hist + layer-0 msg table =================
__global__ __launch_bounds__(256) void hist_msg0(const int* __restrict__ dst,
                                                 int* __restrict__ cnt,
                                                 const float* __restrict__ x,
                                                 const float* __restrict__ p_ptr,
                                                 __hip_bfloat16* __restrict__ msgb) {
  int bid = blockIdx.x;
  int tid = threadIdx.x;
  if (bid < 625) {  // 625*256 == N_EDGES
    atomicAdd(&cnt[dst[bid * 256 + tid]], 1);
    return;
  }
  float p = *p_ptr;
  bool p1 = (p == 1.0f);
  const int total = N_NODES * D_INPUT / 2;
  for (int i = (bid - 625) * 256 + tid; i < total; i += 320000) {
    float2 v = ((const float2*)x)[i];
    float m0 = fminf(fmaxf(v.x, 0.f) + EPS, MAXV);
    float m1 = fminf(fmaxf(v.y, 0.f) + EPS, MAXV);
    if (!p1) { m0 = powf(m0, p); m1 = powf(m1, p); }
    __hip_bfloat162 o;
    o.x = __float2bfloat16(m0);
    o.y = __float2bfloat16(m1);
    ((__hip_bfloat162*)msgb)[i] = o;
  }
}

// single-block scan; reads cnt via int4, writes rowptr via int4, zeroes cnt
__global__ __launch_bounds__(256) void scan_kernel(int* __restrict__ cnt,
                                                   int* __restrict__ rowptr) {
  __shared__ int ps[256];
  int tid = threadIdx.x;
  const int CH = 40;
  int b0 = tid * CH;
  bool active = (b0 < N_NODES);
  int v[CH];
  int s = 0;
  if (active) {
    const int4* c4p = (const int4*)(cnt + b0);
#pragma unroll
    for (int i = 0; i < CH / 4; i++) {
      int4 q = c4p[i];
      v[4 * i] = q.x; v[4 * i + 1] = q.y; v[4 * i + 2] = q.z; v[4 * i + 3] = q.w;
      s += q.x + q.y + q.z + q.w;
    }
  }
  ps[tid] = s;
  __syncthreads();
  for (int off = 1; off < 256; off <<= 1) {
    int t = (tid >= off) ? ps[tid - off] : 0;
    __syncthreads();
    ps[tid] += t;
    __syncthreads();
  }
  int run = (tid == 0) ? 0 : ps[tid - 1];
  if (active) {
    int r[CH];
#pragma unroll
    for (int i = 0; i < CH; i++) { r[i] = run; run += v[i]; }
    int4* rp = (int4*)(rowptr + b0);
    int4* cz = (int4*)(cnt + b0);
#pragma unroll
    for (int i = 0; i < CH / 4; i++) {
      rp[i] = make_int4(r[4 * i], r[4 * i + 1], r[4 * i + 2], r[4 * i + 3]);
      cz[i] = make_int4(0, 0, 0, 0);
    }
  }
  if (tid == 255) rowptr[N_NODES] = ps[255];
}

__global__ __launch_bounds__(256) void scatter_kernel(
    const int* __restrict__ src, const int* __restrict__ dst,
    const int* __restrict__ rowptr, int* __restrict__ cursor,
    int* __restrict__ csr_src) {
  int i = blockIdx.x * blockDim.x + threadIdx.x;
  if (i < N_EDGES) {
    int t = dst[i];
    int pos = rowptr[t] + atomicAdd(&cursor[t], 1);
    csr_src[pos] = src[i];
  }
}

// ============ fused: CSR aggregation (bf16 msg table, 4B gather) + power-mean
//              + MessageNorm + residual (bf16 out). h is post-BN f32. ============
template <int D>
__global__ __launch_bounds__(256) void agg_msgnorm_kernel(
    const float* __restrict__ h, const __hip_bfloat16* __restrict__ msgb,
    const int* __restrict__ rowptr, const int* __restrict__ csr_src,
    const float* __restrict__ p_ptr, const float* __restrict__ scale_ptr,
    __hip_bfloat16* __restrict__ out) {
  constexpr int C = D / 2;
  constexpr int SL = 256 / C;
  int n = blockIdx.x;
  int tid = threadIdx.x;
  int col = tid % C;
  int slice = tid / C;
  int lo = rowptr[n], hi = rowptr[n + 1];
  float p = *p_ptr;
  float scale = *scale_ptr;
  bool p1 = (p == 1.0f);
  float invp = 1.0f / p;
  float inv_dg = 1.0f / fmaxf((float)(hi - lo), 1.0f);
  const float2* h2 = (const float2*)h;
  const uint* mg = (const uint*)msgb;

  __shared__ int s_src[256];  // pre-multiplied row offsets (src * C)
  float accx = 0.f, accy = 0.f;
  for (int base = lo; base < hi; base += 256) {
    int m = min(256, hi - base);
    __syncthreads();
    if (tid < m) s_src[tid] = csr_src[base + tid] * C;
    __syncthreads();
    int j = slice;
    for (; j + 3 * SL < m; j += 4 * SL) {
      uint u0 = mg[s_src[j] + col];
      uint u1 = mg[s_src[j + SL] + col];
      uint u2 = mg[s_src[j + 2 * SL] + col];
      uint u3 = mg[s_src[j + 3 * SL] + col];
      accx += (__uint_as_float(u0 << 16) + __uint_as_float(u1 << 16)) +
              (__uint_as_float(u2 << 16) + __uint_as_float(u3 << 16));
      accy += (__uint_as_float(u0 & 0xFFFF0000u) + __uint_as_float(u1 & 0xFFFF0000u)) +
              (__uint_as_float(u2 & 0xFFFF0000u) + __uint_as_float(u3 & 0xFFFF0000u));
    }
    for (; j < m; j += SL) {
      uint u = mg[s_src[j] + col];
      accx += __uint_as_float(u << 16);
      accy += __uint_as_float(u & 0xFFFF0000u);
    }
  }

  if constexpr (SL > 1) {
    __shared__ float sacc[2][256];
    sacc[0][tid] = accx;
    sacc[1][tid] = accy;
    __syncthreads();
    if (tid < C) {
#pragma unroll
      for (int s = 1; s < SL; s++) {
        accx += sacc[0][s * C + tid];
        accy += sacc[1][s * C + tid];
      }
    }
  }

  float a0 = 0.f, a1 = 0.f, hv0 = 0.f, hv1 = 0.f, sa = 0.f, sh = 0.f;
  if (tid < C) {
    a0 = fminf(fmaxf(accx * inv_dg, EPS), MAXV);
    a1 = fminf(fmaxf(accy * inv_dg, EPS), MAXV);
    if (!p1) { a0 = powf(a0, invp); a1 = powf(a1, invp); }
    float2 hx = h2[(size_t)n * C + tid];
    hv0 = hx.x;
    hv1 = hx.y;
    sa = a0 * a0 + a1 * a1;
    sh = hv0 * hv0 + hv1 * hv1;
  }
  for (int off = 32; off; off >>= 1) {
    sa += __shfl_down(sa, off);
    sh += __shfl_down(sh, off);
  }
  __shared__ float red[2][4];
  __shared__ float tot[2];
  int wid = tid >> 6;
  if ((tid & 63) == 0) { red[0][wid] = sa; red[1][wid] = sh; }
  __syncthreads();
  if (tid == 0) {
    tot[0] = red[0][0] + red[0][1] + red[0][2] + red[0][3];
    tot[1] = red[1][0] + red[1][1] + red[1][2] + red[1][3];
  }
  __syncthreads();
  float k = sqrtf(tot[1]) * scale / fmaxf(sqrtf(tot[0]), 1e-12f);
  if (tid < C) {
    __hip_bfloat162 o2;
    o2.x = __float2bfloat16(hv0 + a0 * k);
    o2.y = __float2bfloat16(hv1 + a1 * k);
    ((__hip_bfloat162*)out)[(size_t)n * C + tid] = o2;
  }
}

// ============ weight convert+transpose (3 mats) + zero {cnt, stats x3, stats4, done} ============
__global__ __launch_bounds__(256) void convert_all(
    const float* __restrict__ W0, const float* __restrict__ Wrest,
    __hip_bfloat16* __restrict__ w0t, __hip_bfloat16* __restrict__ w1t,
    __hip_bfloat16* __restrict__ w2t, int* __restrict__ cnt,
    float* __restrict__ stats, float* __restrict__ stats4,
    int* __restrict__ done) {
  int z = blockIdx.z;
  const float* W;
  __hip_bfloat16* Wt;
  int K;
  if (z == 0) { W = W0; Wt = w0t; K = D_INPUT; }
  else if (z == 1) { W = Wrest; Wt = w1t; K = D_H; }
  else { W = Wrest + (size_t)D_H * D_H; Wt = w2t; K = D_H; }

  if (z == 0 && blockIdx.x >= 4) {
    // spare: zero cnt[10000] + stats[3072] + stats4[1024] + done[4]
    int e = ((blockIdx.x - 4) * 16 + blockIdx.y) * 256 + threadIdx.x;  // 0..49151
    if (e < 10000) cnt[e] = 0;
    else {
      int f = e - 10000;
      if (f < 3072) stats[f] = 0.f;
      else if (f < 4096) stats4[f - 3072] = 0.f;
      else if (f < 4100) done[f - 4096] = 0;
    }
    return;
  }

  __shared__ float tile[32][33];
  int k0 = blockIdx.x * 32, n0 = blockIdx.y * 32;
  int tx = threadIdx.x & 31, ty = threadIdx.x >> 5;
  for (int i = ty; i < 32; i += 8)
    tile[i][tx] = W[(size_t)(k0 + i) * D_H + n0 + tx];
  __syncthreads();
  for (int i = ty; i < 32; i += 8)
    Wt[(size_t)(n0 + i) * K + k0 + tx] = __float2bfloat16(tile[tx][i]);
}

// ============ MFMA bf16 GEMM + stats + LOAD-polling grid barrier + BN/ReLU epilogue ============
// LAYER 0: hout = v (post-BN), msgb = f(v, p_next)
// LAYER 1: hout = v, jk_out = max(jk_in, v), msgb = f(v, p_next)   (jk_in = h0)
// LAYER 2: hout = max(jk_in, v)  (vfull for pooling)
template <int LAYER>
__global__ __launch_bounds__(256, 2) void mfma_gemm_fused(
    const __hip_bfloat16* __restrict__ A, const __hip_bfloat16* __restrict__ Bt,
    const float* __restrict__ bias, float* __restrict__ stats,
    const float* __restrict__ gamma, const float* __restrict__ beta,
    float* __restrict__ hout, const float* __restrict__ jk_in,
    float* __restrict__ jk_out, const float* __restrict__ p_ptr,
    __hip_bfloat16* __restrict__ msgb, int* __restrict__ done, int M, int K) {
  __shared__ ushort As[128 * 64];
  __shared__ ushort Bs[128 * 64];
  __shared__ float sred[128][2];
  int tid = threadIdx.x;
  int l = tid & 63;
  int w = tid >> 6;
  int wm = w >> 1, wn = w & 1;
  int row0 = blockIdx.x * 128;
  int col0 = blockIdx.y * 128;

  f32x4 acc[4][4];
#pragma unroll
  for (int m = 0; m < 4; m++)
#pragma unroll
    for (int n = 0; n < 4; n++) acc[m][n] = (f32x4){0.f, 0.f, 0.f, 0.f};

  const ushort* Ag = (const ushort*)A;
  const ushort* Bg = (const ushort*)Bt;
  char* AsB = (char*)As;
  char* BsB = (char*)Bs;

  if (tid < 128) { sred[tid][0] = 0.f; sred[tid][1] = 0.f; }

  int srow = tid >> 3;
  int scb = (tid & 7) * 16;
  int wbyte = scb ^ ((srow & 7) << 4);
  int scol = scb >> 1;

  int lswz = (l & 7) << 4;
  int kb = (l >> 4) * 16;
  int arow = wm * 64 + (l & 15);
  int brow = wn * 64 + (l & 15);

  for (int k0 = 0; k0 < K; k0 += 64) {
    uint4 ra[4], rb[4];
#pragma unroll
    for (int j = 0; j < 4; j++) {
      int row = j * 32 + srow;
      ra[j] = *(const uint4*)(Ag + (size_t)(row0 + row) * K + k0 + scol);
      rb[j] = *(const uint4*)(Bg + (size_t)(col0 + row) * K + k0 + scol);
    }
#pragma unroll
    for (int j = 0; j < 4; j++) {
      int row = j * 32 + srow;
      *(uint4*)(AsB + row * 128 + wbyte) = ra[j];
      *(uint4*)(BsB + row * 128 + wbyte) = rb[j];
    }
    __syncthreads();
#pragma unroll
    for (int kk = 0; kk < 2; kk++) {
      bf16x8 af[4], bfr[4];
#pragma unroll
      for (int m = 0; m < 4; m++)
        af[m] = *(const bf16x8*)(AsB + (arow + m * 16) * 128 + ((kk * 64 + kb) ^ lswz));
#pragma unroll
      for (int n = 0; n < 4; n++)
        bfr[n] = *(const bf16x8*)(BsB + (brow + n * 16) * 128 + ((kk * 64 + kb) ^ lswz));
#pragma unroll
      for (int m = 0; m < 4; m++)
#pragma unroll
        for (int n = 0; n < 4; n++)
          acc[m][n] = __builtin_amdgcn_mfma_f32_16x16x32_bf16(af[m], bfr[n], acc[m][n], 0, 0, 0);
    }
    __syncthreads();
  }

  int crow0 = row0 + wm * 64 + (l >> 4) * 4;
  int ccol0 = col0 + wn * 64 + (l & 15);

  // ---- per-column partial stats (sum, sumsq of v_lin = acc + bias) ----
#pragma unroll
  for (int n = 0; n < 4; n++) {
    int col = ccol0 + n * 16;
    float bv = bias[col];
    float ps = 0.f, pq = 0.f;
#pragma unroll
    for (int m = 0; m < 4; m++) {
#pragma unroll
      for (int r = 0; r < 4; r++) {
        int rr = crow0 + m * 16 + r;
        if (rr < M) {
          float v = acc[m][n][r] + bv;
          ps += v;
          pq += v * v;
        }
      }
    }
    ps += __shfl_down(ps, 16); pq += __shfl_down(pq, 16);
    ps += __shfl_down(ps, 32); pq += __shfl_down(pq, 32);
    if ((l >> 4) == 0) {
      atomicAdd(&sred[wn * 64 + n * 16 + (l & 15)][0], ps);
      atomicAdd(&sred[wn * 64 + n * 16 + (l & 15)][1], pq);
    }
  }
  __syncthreads();
  if (tid < 128) {
    atomicAdd(&stats[col0 + tid], sred[tid][0]);
    atomicAdd(&stats[D_H + col0 + tid], sred[tid][1]);
  }

  // ---- grid barrier: one ACQ_REL increment; poll with plain ACQUIRE LOADS (no RMW) ----
  __threadfence();
  __syncthreads();
  if (tid == 0) {
    __hip_atomic_fetch_add(done, 1, __ATOMIC_ACQ_REL, __HIP_MEMORY_SCOPE_AGENT);
    while (__hip_atomic_load(done, __ATOMIC_ACQUIRE, __HIP_MEMORY_SCOPE_AGENT) < GEMM_BLOCKS)
      __builtin_amdgcn_s_sleep(16);
  }
  __syncthreads();

  // ---- stage this block's 256 stats values into LDS (coherent agent-scope loads) ----
  float* sstat = (float*)As;  // reuse; [0..127]=sum, [128..255]=sumsq
  {
    int c = tid & 127;
    int which = tid >> 7;
    sstat[tid] = __hip_atomic_load(&stats[which * D_H + col0 + c],
                                   __ATOMIC_RELAXED, __HIP_MEMORY_SCOPE_AGENT);
  }
  __syncthreads();

  // ---- BN affine + ReLU on register accumulators; emit h / jk / msgb ----
  const float invN = 1.0f / (float)N_NODES;
  float pnext = 1.f;
  bool p1 = true;
  if constexpr (LAYER < 2) {
    pnext = *p_ptr;
    p1 = (pnext == 1.0f);
  }
#pragma unroll
  for (int n = 0; n < 4; n++) {
    int col = ccol0 + n * 16;
    float bv = bias[col];
    float mean = sstat[col - col0] * invN;
    float var = sstat[128 + col - col0] * invN - mean * mean;
    float sc = rsqrtf(var + BN_EPS) * gamma[col];
    float shf = beta[col] - mean * sc;
#pragma unroll
    for (int m = 0; m < 4; m++) {
#pragma unroll
      for (int r = 0; r < 4; r++) {
        int rr = crow0 + m * 16 + r;
        if (rr < M) {
          size_t idx = (size_t)rr * D_H + col;
          float v = fmaxf((acc[m][n][r] + bv) * sc + shf, 0.f);
          if constexpr (LAYER == 0) {
            hout[idx] = v;
          } else if constexpr (LAYER == 1) {
            hout[idx] = v;
            jk_out[idx] = fmaxf(jk_in[idx], v);
          } else {
            hout[idx] = fmaxf(jk_in[idx], v);
          }
          if constexpr (LAYER < 2) {
            float mm = fminf(v + EPS, MAXV);
            if (!p1) mm = powf(mm, pnext);
            msgb[idx] = __float2bfloat16(mm);
          }
        }
      }
    }
  }
}

// ---------------- per-graph max+mean pooling (float4, divides mean) ----------------
__device__ __forceinline__ int lower_bound_i(const int* a, int n, int v) {
  int lo = 0, hi = n;
  while (lo < hi) {
    int mid = (lo + hi) >> 1;
    if (a[mid] < v) lo = mid + 1; else hi = mid;
  }
  return lo;
}

__global__ __launch_bounds__(256) void pool_kernel(const float* __restrict__ jk,
                                                   const int* __restrict__ batch,
                                                   float* __restrict__ g) {
  int gid = blockIdx.x;
  int cl = threadIdx.x & 15;
  int slice = threadIdx.x >> 4;
  int f4c = blockIdx.y * 16 + cl;  // 0..127
  int lo = lower_bound_i(batch, N_NODES, gid);
  int hi = lower_bound_i(batch, N_NODES, gid + 1);
  const float4* J = (const float4*)jk;
  float4 mx = make_float4(0.f, 0.f, 0.f, 0.f);
  float4 sm = make_float4(0.f, 0.f, 0.f, 0.f);
  int r = lo + slice;
  for (; r + 16 < hi; r += 32) {
    float4 v0 = J[(size_t)r * 128 + f4c];
    float4 v1 = J[(size_t)(r + 16) * 128 + f4c];
    mx.x = fmaxf(fmaxf(mx.x, v0.x), v1.x);
    mx.y = fmaxf(fmaxf(mx.y, v0.y), v1.y);
    mx.z = fmaxf(fmaxf(mx.z, v0.z), v1.z);
    mx.w = fmaxf(fmaxf(mx.w, v0.w), v1.w);
    sm.x += v0.x + v1.x; sm.y += v0.y + v1.y;
    sm.z += v0.z + v1.z; sm.w += v0.w + v1.w;
  }
  for (; r < hi; r += 16) {
    float4 v = J[(size_t)r * 128 + f4c];
    mx.x = fmaxf(mx.x, v.x); mx.y = fmaxf(mx.y, v.y);
    mx.z = fmaxf(mx.z, v.z); mx.w = fmaxf(mx.w, v.w);
    sm.x += v.x; sm.y += v.y; sm.z += v.z; sm.w += v.w;
  }
  __shared__ float4 smax[16][16];
  __shared__ float4 ssum[16][16];
  smax[slice][cl] = mx;
  ssum[slice][cl] = sm;
  __syncthreads();
  if (slice == 0) {
#pragma unroll
    for (int s = 1; s < 16; s++) {
      float4 m2 = smax[s][cl], s2 = ssum[s][cl];
      mx.x = fmaxf(mx.x, m2.x); mx.y = fmaxf(mx.y, m2.y);
      mx.z = fmaxf(mx.z, m2.z); mx.w = fmaxf(mx.w, m2.w);
      sm.x += s2.x; sm.y += s2.y; sm.z += s2.z; sm.w += s2.w;
    }
    float ic = 1.0f / fmaxf((float)(hi - lo), 1.0f);
    if (hi <= lo) mx = make_float4(0.f, 0.f, 0.f, 0.f);
    sm.x *= ic; sm.y *= ic; sm.z *= ic; sm.w *= ic;
    ((float4*)(g + (size_t)gid * 1024))[f4c] = mx;
    ((float4*)(g + (size_t)gid * 1024 + D_H))[f4c] = sm;
  }
}

// ---------------- fc1 (+ fused column stats for bn4) ----------------
__global__ __launch_bounds__(256) void fc1_kernel(const float* __restrict__ g,
                                                  const float* __restrict__ W,
                                                  const float* __restrict__ b,
                                                  float* __restrict__ out,
                                                  float* __restrict__ stats4) {
  __shared__ float sg[1024];
  __shared__ float sred[4][64];
  int gid = blockIdx.x;
  int tid = threadIdx.x;
  ((float4*)sg)[tid] = ((const float4*)(g + (size_t)gid * 1024))[tid];
  __syncthreads();
  int cl = tid & 63;
  int slice = tid >> 6;
  int col = blockIdx.y * 64 + cl;
  int k0 = slice * 256;
  float acc = 0.f;
#pragma unroll 4
  for (int k = k0; k < k0 + 256; k++) acc += sg[k] * W[(size_t)k * D_H + col];
  sred[slice][cl] = acc;
  __syncthreads();
  if (slice == 0) {
    float v = sred[0][cl] + sred[1][cl] + sred[2][cl] + sred[3][cl] + b[col];
    out[(size_t)gid * D_H + col] = v;
    atomicAdd(&stats4[col], v);
    atomicAdd(&stats4[D_H + col], v * v);
  }
}

// ---------------- fc2 with inline bn4 (stats4) ----------------
__global__ __launch_bounds__(64) void fc2_kernel(const float* __restrict__ y,
                                                 const float* __restrict__ stats4,
                                                 const float* __restrict__ gmm,
                                                 const float* __restrict__ bb,
                                                 const float* __restrict__ W,
                                                 const float* __restrict__ b,
                                                 float* __restrict__ out) {
  int gid = blockIdx.x;
  int lane = threadIdx.x;
  const float invG = 1.0f / (float)N_GRAPHS;
  float a0 = 0.f, a1 = 0.f;
#pragma unroll
  for (int j = 0; j < 8; j++) {
    int k = lane + j * 64;
    float mean = stats4[k] * invG;
    float var = stats4[D_H + k] * invG - mean * mean;
    float sc = rsqrtf(var + BN_EPS) * gmm[k];
    float v = fmaxf(y[(size_t)gid * D_H + k] * sc + bb[k] - mean * sc, 0.f);
    a0 += v * W[k * 2 + 0];
    a1 += v * W[k * 2 + 1];
  }
  for (int off = 32; off; off >>= 1) {
    a0 += __shfl_down(a0, off);
    a1 += __shfl_down(a1, off);
  }
  if (lane == 0) {
    out[gid * 2 + 0] = a0 + b[0];
    out[gid * 2 + 1] = a1 + b[1];
  }
}

extern "C" void kernel_launch(void* const* d_in, const int* in_sizes, int n_in,
                              void* d_out, int out_size, void* d_ws, size_t ws_size,
                              hipStream_t stream) {
  const float* x       = (const float*)d_in[0];
  const float* W0      = (const float*)d_in[1];
  const float* Wrest   = (const float*)d_in[2];
  const float* bconv   = (const float*)d_in[3];
  const float* p       = (const float*)d_in[4];
  const float* mscale  = (const float*)d_in[5];
  const float* bn_g    = (const float*)d_in[6];
  const float* bn_b    = (const float*)d_in[7];
  const float* fc1_W   = (const float*)d_in[8];
  const float* fc1_b   = (const float*)d_in[9];
  const float* bn4_g   = (const float*)d_in[10];
  const float* bn4_b   = (const float*)d_in[11];
  const float* fc2_W   = (const float*)d_in[12];
  const float* fc2_b   = (const float*)d_in[13];
  const int*   eidx    = (const int*)d_in[14];
  const int*   batch   = (const int*)d_in[15];
  float* out = (float*)d_out;

  const int* src = eidx;
  const int* dst = eidx + N_EDGES;

  float* ws = (float*)d_ws;
  const size_t NH = (size_t)N_NODES * D_H;
  float* h0     = ws;                 // v0 (post-BN); reused as vfull after layer 2
  float* h1     = h0 + NH;            // v1 (post-BN)
  float* jk     = h1 + NH;            // max(v0, v1)
  float* stats  = jk + NH;            // 3 x 1024
  float* stats4 = stats + 3072;       // 1024
  int*   done   = (int*)(stats4 + 1024);  // 4
  __hip_bfloat16* residb = (__hip_bfloat16*)(done + 4);     // [M_PAD][512]
  __hip_bfloat16* msgb = residb + (size_t)M_PAD * D_H;      // [N_NODES][512]
  __hip_bfloat16* w0t = msgb + NH;
  __hip_bfloat16* w1t = w0t + 512 * 128;
  __hip_bfloat16* w2t = w1t + 512 * 512;
  int* cnt     = (int*)(w2t + 512 * 512);
  int* rowptr  = cnt + N_NODES;
  int* csr_src = rowptr + N_NODES + 1;
  float* g     = (float*)(csr_src + N_EDGES);   // [64][1024]: max | mean
  float* g2lin = g + 64 * 1024;                 // [64][512]

  // weights + zero {cnt, stats, stats4, done}
  convert_all<<<dim3(16, 16, 3), 256, 0, stream>>>(W0, Wrest, w0t, w1t, w2t,
                                                   cnt, stats, stats4, done);
  // CSR + layer-0 msg table
  hist_msg0<<<1875, 256, 0, stream>>>(dst, cnt, x, p, msgb);
  scan_kernel<<<1, 256, 0, stream>>>(cnt, rowptr);
  scatter_kernel<<<(N_EDGES + 255) / 256, 256, 0, stream>>>(src, dst, rowptr, cnt, csr_src);

  // ---- layer 0 ----
  agg_msgnorm_kernel<D_INPUT><<<N_NODES, 256, 0, stream>>>(
      x, msgb, rowptr, csr_src, p + 0, mscale + 0, residb);
  mfma_gemm_fused<0><<<dim3(79, 4), 256, 0, stream>>>(
      residb, w0t, bconv, stats, bn_g, bn_b,
      h0, nullptr, nullptr, p + 1, msgb, done + 0, N_NODES, D_INPUT);

  // ---- layer 1 ----
  agg_msgnorm_kernel<D_H><<<N_NODES, 256, 0, stream>>>(
      h0, msgb, rowptr, csr_src, p + 1, mscale + 1, residb);
  mfma_gemm_fused<1><<<dim3(79, 4), 256, 0, stream>>>(
      residb, w1t, bconv + D_H, stats + 1024, bn_g + D_H, bn_b + D_H,
      h1, h0, jk, p + 2, msgb, done + 1, N_NODES, D_H);

  // ---- layer 2 ----
  agg_msgnorm_kernel<D_H><<<N_NODES, 256, 0, stream>>>(
      h1, msgb, rowptr, csr_src, p + 2, mscale + 2, residb);
  mfma_gemm_fused<2><<<dim3(79, 4), 256, 0, stream>>>(
      residb, w2t, bconv + 2 * D_H, stats + 2048, bn_g + 2 * D_H, bn_b + 2 * D_H,
      h0 /*vfull*/, jk, nullptr, nullptr, nullptr, done + 2, N_NODES, D_H);

  // ---- head ----
  pool_kernel<<<dim3(N_GRAPHS, 8), 256, 0, stream>>>(h0, batch, g);
  fc1_kernel<<<dim3(N_GRAPHS, 8), 256, 0, stream>>>(g, fc1_W, fc1_b, g2lin, stats4);
  fc2_kernel<<<N_GRAPHS, 64, 0, stream>>>(g2lin, stats4, bn4_g, bn4_b, fc2_W, fc2_b, out);
}

// Round 14
// 244.109 us; speedup vs baseline: 1.6534x; 1.6534x over previous
//
#include <hip/hip_runtime.h>
#include <hip/hip_bf16.h>
#include <math.h>

#define N_NODES 10000
#define N_GRAPHS 64
#define N_EDGES 160000
#define D_INPUT 128
#define D_H 512
#define EPS 1e-7f
#define MAXV 10.0f
#define BN_EPS 1e-5f
#define M_PAD 10112  // 79 * 128

typedef __attribute__((ext_vector_type(4))) float f32x4;
typedef __attribute__((ext_vector_type(8))) __bf16 bf16x8;

// ================= fused hist + layer-0 msg table =================
__global__ __launch_bounds__(256) void hist_msg0(const int* __restrict__ dst,
                                                 int* __restrict__ cnt,
                                                 const float* __restrict__ x,
                                                 const float* __restrict__ p_ptr,
                                                 __hip_bfloat16* __restrict__ msgb) {
  int bid = blockIdx.x;
  int tid = threadIdx.x;
  if (bid < 625) {  // 625*256 == N_EDGES
    atomicAdd(&cnt[dst[bid * 256 + tid]], 1);
    return;
  }
  float p = *p_ptr;
  bool p1 = (p == 1.0f);
  const int total = N_NODES * D_INPUT / 2;
  for (int i = (bid - 625) * 256 + tid; i < total; i += 320000) {
    float2 v = ((const float2*)x)[i];
    float m0 = fminf(fmaxf(v.x, 0.f) + EPS, MAXV);
    float m1 = fminf(fmaxf(v.y, 0.f) + EPS, MAXV);
    if (!p1) { m0 = powf(m0, p); m1 = powf(m1, p); }
    __hip_bfloat162 o;
    o.x = __float2bfloat16(m0);
    o.y = __float2bfloat16(m1);
    ((__hip_bfloat162*)msgb)[i] = o;
  }
}

// single-block scan; reads cnt via int4, writes rowptr via int4, zeroes cnt
__global__ __launch_bounds__(256) void scan_kernel(int* __restrict__ cnt,
                                                   int* __restrict__ rowptr) {
  __shared__ int ps[256];
  int tid = threadIdx.x;
  const int CH = 40;
  int b0 = tid * CH;
  bool active = (b0 < N_NODES);
  int v[CH];
  int s = 0;
  if (active) {
    const int4* c4p = (const int4*)(cnt + b0);
#pragma unroll
    for (int i = 0; i < CH / 4; i++) {
      int4 q = c4p[i];
      v[4 * i] = q.x; v[4 * i + 1] = q.y; v[4 * i + 2] = q.z; v[4 * i + 3] = q.w;
      s += q.x + q.y + q.z + q.w;
    }
  }
  ps[tid] = s;
  __syncthreads();
  for (int off = 1; off < 256; off <<= 1) {
    int t = (tid >= off) ? ps[tid - off] : 0;
    __syncthreads();
    ps[tid] += t;
    __syncthreads();
  }
  int run = (tid == 0) ? 0 : ps[tid - 1];
  if (active) {
    int r[CH];
#pragma unroll
    for (int i = 0; i < CH; i++) { r[i] = run; run += v[i]; }
    int4* rp = (int4*)(rowptr + b0);
    int4* cz = (int4*)(cnt + b0);
#pragma unroll
    for (int i = 0; i < CH / 4; i++) {
      rp[i] = make_int4(r[4 * i], r[4 * i + 1], r[4 * i + 2], r[4 * i + 3]);
      cz[i] = make_int4(0, 0, 0, 0);
    }
  }
  if (tid == 255) rowptr[N_NODES] = ps[255];
}

__global__ __launch_bounds__(256) void scatter_kernel(
    const int* __restrict__ src, const int* __restrict__ dst,
    const int* __restrict__ rowptr, int* __restrict__ cursor,
    int* __restrict__ csr_src) {
  int i = blockIdx.x * blockDim.x + threadIdx.x;
  if (i < N_EDGES) {
    int t = dst[i];
    int pos = rowptr[t] + atomicAdd(&cursor[t], 1);
    csr_src[pos] = src[i];
  }
}

// ============ fused: CSR aggregation (bf16 msg table, 4B gather) + power-mean
//              + MessageNorm + residual (bf16 out) ============
template <int D, bool BN>
__global__ __launch_bounds__(256) void agg_msgnorm_kernel(
    const float* __restrict__ h, const float* __restrict__ aff,
    const __hip_bfloat16* __restrict__ msgb,
    const int* __restrict__ rowptr, const int* __restrict__ csr_src,
    const float* __restrict__ p_ptr, const float* __restrict__ scale_ptr,
    __hip_bfloat16* __restrict__ out) {
  constexpr int C = D / 2;
  constexpr int SL = 256 / C;
  int n = blockIdx.x;
  int tid = threadIdx.x;
  int col = tid % C;
  int slice = tid / C;
  int lo = rowptr[n], hi = rowptr[n + 1];
  float p = *p_ptr;
  float scale = *scale_ptr;
  bool p1 = (p == 1.0f);
  float invp = 1.0f / p;
  float inv_dg = 1.0f / fmaxf((float)(hi - lo), 1.0f);
  const float2* h2 = (const float2*)h;
  const uint* mg = (const uint*)msgb;

  __shared__ int s_src[256];  // pre-multiplied row offsets (src * C)
  float accx = 0.f, accy = 0.f;
  for (int base = lo; base < hi; base += 256) {
    int m = min(256, hi - base);
    __syncthreads();
    if (tid < m) s_src[tid] = csr_src[base + tid] * C;
    __syncthreads();
    int j = slice;
    for (; j + 3 * SL < m; j += 4 * SL) {
      uint u0 = mg[s_src[j] + col];
      uint u1 = mg[s_src[j + SL] + col];
      uint u2 = mg[s_src[j + 2 * SL] + col];
      uint u3 = mg[s_src[j + 3 * SL] + col];
      accx += (__uint_as_float(u0 << 16) + __uint_as_float(u1 << 16)) +
              (__uint_as_float(u2 << 16) + __uint_as_float(u3 << 16));
      accy += (__uint_as_float(u0 & 0xFFFF0000u) + __uint_as_float(u1 & 0xFFFF0000u)) +
              (__uint_as_float(u2 & 0xFFFF0000u) + __uint_as_float(u3 & 0xFFFF0000u));
    }
    for (; j < m; j += SL) {
      uint u = mg[s_src[j] + col];
      accx += __uint_as_float(u << 16);
      accy += __uint_as_float(u & 0xFFFF0000u);
    }
  }

  if constexpr (SL > 1) {
    __shared__ float sacc[2][256];
    sacc[0][tid] = accx;
    sacc[1][tid] = accy;
    __syncthreads();
    if (tid < C) {
#pragma unroll
      for (int s = 1; s < SL; s++) {
        accx += sacc[0][s * C + tid];
        accy += sacc[1][s * C + tid];
      }
    }
  }

  float a0 = 0.f, a1 = 0.f, hv0 = 0.f, hv1 = 0.f, sa = 0.f, sh = 0.f;
  if (tid < C) {
    a0 = fminf(fmaxf(accx * inv_dg, EPS), MAXV);
    a1 = fminf(fmaxf(accy * inv_dg, EPS), MAXV);
    if (!p1) { a0 = powf(a0, invp); a1 = powf(a1, invp); }
    float2 hx = h2[(size_t)n * C + tid];
    if constexpr (BN) {
      float2 s2 = ((const float2*)aff)[tid];
      float2 b2 = ((const float2*)(aff + D_H))[tid];
      hx.x = fmaxf(hx.x * s2.x + b2.x, 0.f);
      hx.y = fmaxf(hx.y * s2.y + b2.y, 0.f);
    }
    hv0 = hx.x;
    hv1 = hx.y;
    sa = a0 * a0 + a1 * a1;
    sh = hv0 * hv0 + hv1 * hv1;
  }
  for (int off = 32; off; off >>= 1) {
    sa += __shfl_down(sa, off);
    sh += __shfl_down(sh, off);
  }
  __shared__ float red[2][4];
  __shared__ float tot[2];
  int wid = tid >> 6;
  if ((tid & 63) == 0) { red[0][wid] = sa; red[1][wid] = sh; }
  __syncthreads();
  if (tid == 0) {
    tot[0] = red[0][0] + red[0][1] + red[0][2] + red[0][3];
    tot[1] = red[1][0] + red[1][1] + red[1][2] + red[1][3];
  }
  __syncthreads();
  float k = sqrtf(tot[1]) * scale / fmaxf(sqrtf(tot[0]), 1e-12f);
  if (tid < C) {
    __hip_bfloat162 o2;
    o2.x = __float2bfloat16(hv0 + a0 * k);
    o2.y = __float2bfloat16(hv1 + a1 * k);
    ((__hip_bfloat162*)out)[(size_t)n * C + tid] = o2;
  }
}

// ============ weight convert+transpose (3 mats) + zero {cnt, stats x3, stats4, g} ============
__global__ __launch_bounds__(256) void convert_all(
    const float* __restrict__ W0, const float* __restrict__ Wrest,
    __hip_bfloat16* __restrict__ w0t, __hip_bfloat16* __restrict__ w1t,
    __hip_bfloat16* __restrict__ w2t, int* __restrict__ cnt,
    float* __restrict__ stats, float* __restrict__ stats4,
    float* __restrict__ g) {
  int z = blockIdx.z;
  const float* W;
  __hip_bfloat16* Wt;
  int K;
  if (z == 0) { W = W0; Wt = w0t; K = D_INPUT; }
  else if (z == 1) { W = Wrest; Wt = w1t; K = D_H; }
  else { W = Wrest + (size_t)D_H * D_H; Wt = w2t; K = D_H; }

  if (z == 0 && blockIdx.x >= 4) {
    // spare: zero cnt[10000] + stats[3072] + stats4[1024] + g[65536]
    int base = ((blockIdx.x - 4) * 16 + blockIdx.y) * 256 + threadIdx.x;  // 0..49151
    const int TOT = 10000 + 3072 + 1024 + 65536;                          // 79632
    for (int e = base; e < TOT; e += 49152) {
      if (e < 10000) cnt[e] = 0;
      else {
        int f = e - 10000;
        if (f < 3072) stats[f] = 0.f;
        else if (f < 4096) stats4[f - 3072] = 0.f;
        else g[f - 4096] = 0.f;
      }
    }
    return;
  }

  __shared__ float tile[32][33];
  int k0 = blockIdx.x * 32, n0 = blockIdx.y * 32;
  int tx = threadIdx.x & 31, ty = threadIdx.x >> 5;
  for (int i = ty; i < 32; i += 8)
    tile[i][tx] = W[(size_t)(k0 + i) * D_H + n0 + tx];
  __syncthreads();
  for (int i = ty; i < 32; i += 8)
    Wt[(size_t)(n0 + i) * K + k0 + tx] = __float2bfloat16(tile[tx][i]);
}

// ============ MFMA bf16 GEMM + fused column stats ============
__global__ __launch_bounds__(256) void mfma_gemm(
    const __hip_bfloat16* __restrict__ A, const __hip_bfloat16* __restrict__ Bt,
    const float* __restrict__ bias, float* __restrict__ C, float* __restrict__ stats,
    int M, int K) {
  __shared__ ushort As[128 * 64];
  __shared__ ushort Bs[128 * 64];
  __shared__ float sred[128][2];
  int tid = threadIdx.x;
  int l = tid & 63;
  int w = tid >> 6;
  int wm = w >> 1, wn = w & 1;
  int row0 = blockIdx.x * 128;
  int col0 = blockIdx.y * 128;

  f32x4 acc[4][4];
#pragma unroll
  for (int m = 0; m < 4; m++)
#pragma unroll
    for (int n = 0; n < 4; n++) acc[m][n] = (f32x4){0.f, 0.f, 0.f, 0.f};

  const ushort* Ag = (const ushort*)A;
  const ushort* Bg = (const ushort*)Bt;
  char* AsB = (char*)As;
  char* BsB = (char*)Bs;

  if (tid < 128) { sred[tid][0] = 0.f; sred[tid][1] = 0.f; }

  int srow = tid >> 3;
  int scb = (tid & 7) * 16;
  int wbyte = scb ^ ((srow & 7) << 4);
  int scol = scb >> 1;

  int lswz = (l & 7) << 4;
  int kb = (l >> 4) * 16;
  int arow = wm * 64 + (l & 15);
  int brow = wn * 64 + (l & 15);

  for (int k0 = 0; k0 < K; k0 += 64) {
    uint4 ra[4], rb[4];
#pragma unroll
    for (int j = 0; j < 4; j++) {
      int row = j * 32 + srow;
      ra[j] = *(const uint4*)(Ag + (size_t)(row0 + row) * K + k0 + scol);
      rb[j] = *(const uint4*)(Bg + (size_t)(col0 + row) * K + k0 + scol);
    }
#pragma unroll
    for (int j = 0; j < 4; j++) {
      int row = j * 32 + srow;
      *(uint4*)(AsB + row * 128 + wbyte) = ra[j];
      *(uint4*)(BsB + row * 128 + wbyte) = rb[j];
    }
    __syncthreads();
#pragma unroll
    for (int kk = 0; kk < 2; kk++) {
      bf16x8 af[4], bfr[4];
#pragma unroll
      for (int m = 0; m < 4; m++)
        af[m] = *(const bf16x8*)(AsB + (arow + m * 16) * 128 + ((kk * 64 + kb) ^ lswz));
#pragma unroll
      for (int n = 0; n < 4; n++)
        bfr[n] = *(const bf16x8*)(BsB + (brow + n * 16) * 128 + ((kk * 64 + kb) ^ lswz));
#pragma unroll
      for (int m = 0; m < 4; m++)
#pragma unroll
        for (int n = 0; n < 4; n++)
          acc[m][n] = __builtin_amdgcn_mfma_f32_16x16x32_bf16(af[m], bfr[n], acc[m][n], 0, 0, 0);
    }
    __syncthreads();
  }

  int crow0 = row0 + wm * 64 + (l >> 4) * 4;
  int ccol0 = col0 + wn * 64 + (l & 15);
#pragma unroll
  for (int n = 0; n < 4; n++) {
    int col = ccol0 + n * 16;
    float bv = bias[col];
    float ps = 0.f, pq = 0.f;
#pragma unroll
    for (int m = 0; m < 4; m++) {
#pragma unroll
      for (int r = 0; r < 4; r++) {
        int rr = crow0 + m * 16 + r;
        if (rr < M) {
          float v = acc[m][n][r] + bv;
          C[(size_t)rr * D_H + col] = v;
          ps += v;
          pq += v * v;
        }
      }
    }
    ps += __shfl_down(ps, 16); pq += __shfl_down(pq, 16);
    ps += __shfl_down(ps, 32); pq += __shfl_down(pq, 32);
    if ((l >> 4) == 0) {
      atomicAdd(&sred[wn * 64 + n * 16 + (l & 15)][0], ps);
      atomicAdd(&sred[wn * 64 + n * 16 + (l & 15)][1], pq);
    }
  }
  __syncthreads();
  if (tid < 128) {
    atomicAdd(&stats[col0 + tid], sred[tid][0]);
    atomicAdd(&stats[D_H + col0 + tid], sred[tid][1]);
  }
}

// ---------------- JK update + next-layer msg table; BN-affine computed inline
//                  from stats; block 0 publishes aff for the next agg ----------------
__global__ __launch_bounds__(256) void jk_msg_update(
    const float* __restrict__ hlin, const float* __restrict__ stats,
    const float* __restrict__ gamma, const float* __restrict__ beta,
    float* __restrict__ jk, const float* __restrict__ p_ptr,
    __hip_bfloat16* __restrict__ msgb, float* __restrict__ aff, int layer) {
  float p = *p_ptr;
  bool p1 = (p == 1.0f);
  const float invN = 1.0f / (float)N_NODES;
  const int total = N_NODES * D_H / 4;
  for (int idx = blockIdx.x * blockDim.x + threadIdx.x; idx < total;
       idx += gridDim.x * blockDim.x) {
    int c4 = idx & 127;
    float4 s4 = ((const float4*)stats)[c4];
    float4 q4 = ((const float4*)(stats + D_H))[c4];
    float4 g4 = ((const float4*)gamma)[c4];
    float4 b4 = ((const float4*)beta)[c4];
    float4 sc, sh;
    {
      float m0 = s4.x * invN, m1 = s4.y * invN, m2 = s4.z * invN, m3 = s4.w * invN;
      sc.x = rsqrtf(q4.x * invN - m0 * m0 + BN_EPS) * g4.x;
      sc.y = rsqrtf(q4.y * invN - m1 * m1 + BN_EPS) * g4.y;
      sc.z = rsqrtf(q4.z * invN - m2 * m2 + BN_EPS) * g4.z;
      sc.w = rsqrtf(q4.w * invN - m3 * m3 + BN_EPS) * g4.w;
      sh.x = b4.x - m0 * sc.x;
      sh.y = b4.y - m1 * sc.y;
      sh.z = b4.z - m2 * sc.z;
      sh.w = b4.w - m3 * sc.w;
    }
    if (idx < 128) {  // block 0, first pass: publish aff
      ((float4*)aff)[idx] = sc;
      ((float4*)(aff + D_H))[idx] = sh;
    }
    float4 x = ((const float4*)hlin)[idx];
    float4 v;
    v.x = fmaxf(x.x * sc.x + sh.x, 0.f);
    v.y = fmaxf(x.y * sc.y + sh.y, 0.f);
    v.z = fmaxf(x.z * sc.z + sh.z, 0.f);
    v.w = fmaxf(x.w * sc.w + sh.w, 0.f);
    {
      float m0 = fminf(v.x + EPS, MAXV);
      float m1 = fminf(v.y + EPS, MAXV);
      float m2 = fminf(v.z + EPS, MAXV);
      float m3 = fminf(v.w + EPS, MAXV);
      if (!p1) { m0 = powf(m0, p); m1 = powf(m1, p); m2 = powf(m2, p); m3 = powf(m3, p); }
      __hip_bfloat162 o01, o23;
      o01.x = __float2bfloat16(m0); o01.y = __float2bfloat16(m1);
      o23.x = __float2bfloat16(m2); o23.y = __float2bfloat16(m3);
      ((__hip_bfloat162*)msgb)[2 * idx] = o01;
      ((__hip_bfloat162*)msgb)[2 * idx + 1] = o23;
    }
    if (layer != 0) {
      float4 j = ((const float4*)jk)[idx];
      v.x = fmaxf(v.x, j.x);
      v.y = fmaxf(v.y, j.y);
      v.z = fmaxf(v.z, j.z);
      v.w = fmaxf(v.w, j.w);
    }
    ((float4*)jk)[idx] = v;
  }
}

// ---------------- layer-2: BN inline + jk-max + fused per-graph pooling ----------------
__global__ __launch_bounds__(256) void jk_pool_kernel(
    const float* __restrict__ hlin, const float* __restrict__ stats,
    const float* __restrict__ gamma, const float* __restrict__ beta,
    const float* __restrict__ jk, const int* __restrict__ batch,
    float* __restrict__ g) {
  int tid = threadIdx.x;
  int f4l = tid & 31;
  int rs = tid >> 5;
  int row0 = blockIdx.x * 128;
  int c4 = blockIdx.y * 32 + f4l;

  __shared__ int s_batch[128];
  __shared__ int lmax[4][32][4];
  __shared__ float lsum[4][32][4];
  if (tid < 128) {
    int r = row0 + tid;
    s_batch[tid] = (r < N_NODES) ? batch[r] : -1;
  }
  for (int i = tid; i < 512; i += 256) {
    ((int*)lmax)[i] = 0;
    ((float*)lsum)[i] = 0.f;
  }
  __syncthreads();
  int g_first = s_batch[0];

  const float invN = 1.0f / (float)N_NODES;
  float4 s4 = ((const float4*)stats)[c4];
  float4 q4 = ((const float4*)(stats + D_H))[c4];
  float4 g4 = ((const float4*)gamma)[c4];
  float4 b4 = ((const float4*)beta)[c4];
  float4 sc, sh;
  {
    float m0 = s4.x * invN, m1 = s4.y * invN, m2 = s4.z * invN, m3 = s4.w * invN;
    sc.x = rsqrtf(q4.x * invN - m0 * m0 + BN_EPS) * g4.x;
    sc.y = rsqrtf(q4.y * invN - m1 * m1 + BN_EPS) * g4.y;
    sc.z = rsqrtf(q4.z * invN - m2 * m2 + BN_EPS) * g4.z;
    sc.w = rsqrtf(q4.w * invN - m3 * m3 + BN_EPS) * g4.w;
    sh.x = b4.x - m0 * sc.x;
    sh.y = b4.y - m1 * sc.y;
    sh.z = b4.z - m2 * sc.z;
    sh.w = b4.w - m3 * sc.w;
  }

  float4 mx = make_float4(0.f, 0.f, 0.f, 0.f);
  float4 sm = make_float4(0.f, 0.f, 0.f, 0.f);
  int cur = -1;

#define FLUSH()                                                              \
  do {                                                                       \
    int slot = cur - g_first;                                                \
    if (slot < 4) {                                                          \
      atomicMax(&lmax[slot][f4l][0], __float_as_int(mx.x));                  \
      atomicMax(&lmax[slot][f4l][1], __float_as_int(mx.y));                  \
      atomicMax(&lmax[slot][f4l][2], __float_as_int(mx.z));                  \
      atomicMax(&lmax[slot][f4l][3], __float_as_int(mx.w));                  \
      atomicAdd(&lsum[slot][f4l][0], sm.x);                                  \
      atomicAdd(&lsum[slot][f4l][1], sm.y);                                  \
      atomicAdd(&lsum[slot][f4l][2], sm.z);                                  \
      atomicAdd(&lsum[slot][f4l][3], sm.w);                                  \
    } else {                                                                 \
      int cb = c4 * 4;                                                       \
      atomicMax((int*)&g[(size_t)cur * 1024 + cb + 0], __float_as_int(mx.x)); \
      atomicMax((int*)&g[(size_t)cur * 1024 + cb + 1], __float_as_int(mx.y)); \
      atomicMax((int*)&g[(size_t)cur * 1024 + cb + 2], __float_as_int(mx.z)); \
      atomicMax((int*)&g[(size_t)cur * 1024 + cb + 3], __float_as_int(mx.w)); \
      atomicAdd(&g[(size_t)cur * 1024 + 512 + cb + 0], sm.x);                \
      atomicAdd(&g[(size_t)cur * 1024 + 512 + cb + 1], sm.y);                \
      atomicAdd(&g[(size_t)cur * 1024 + 512 + cb + 2], sm.z);                \
      atomicAdd(&g[(size_t)cur * 1024 + 512 + cb + 3], sm.w);                \
    }                                                                        \
  } while (0)

  for (int i = 0; i < 16; i++) {
    int r = row0 + rs + i * 8;
    if (r >= N_NODES) break;
    int gg = s_batch[rs + i * 8];
    if (gg != cur) {
      if (cur >= 0) FLUSH();
      cur = gg;
      mx = make_float4(0.f, 0.f, 0.f, 0.f);
      sm = make_float4(0.f, 0.f, 0.f, 0.f);
    }
    float4 x = ((const float4*)hlin)[(size_t)r * 128 + c4];
    float4 j4 = ((const float4*)jk)[(size_t)r * 128 + c4];
    float4 v;
    v.x = fmaxf(fmaxf(x.x * sc.x + sh.x, 0.f), j4.x);
    v.y = fmaxf(fmaxf(x.y * sc.y + sh.y, 0.f), j4.y);
    v.z = fmaxf(fmaxf(x.z * sc.z + sh.z, 0.f), j4.z);
    v.w = fmaxf(fmaxf(x.w * sc.w + sh.w, 0.f), j4.w);
    mx.x = fmaxf(mx.x, v.x); mx.y = fmaxf(mx.y, v.y);
    mx.z = fmaxf(mx.z, v.z); mx.w = fmaxf(mx.w, v.w);
    sm.x += v.x; sm.y += v.y; sm.z += v.z; sm.w += v.w;
  }
  if (cur >= 0) FLUSH();
#undef FLUSH
  __syncthreads();

  int last = min(127, N_NODES - 1 - row0);
  int g_last = s_batch[last];
  int ns = min(3, g_last - g_first);
  for (int s = 0; s <= ns; s++) {
    int gi = g_first + s;
    if (tid < 128) {
      int fc = tid >> 2, comp = tid & 3;
      int col = (blockIdx.y * 32 + fc) * 4 + comp;
      atomicMax((int*)&g[(size_t)gi * 1024 + col], lmax[s][fc][comp]);
    } else {
      int t = tid - 128;
      int fc = t >> 2, comp = t & 3;
      int col = (blockIdx.y * 32 + fc) * 4 + comp;
      atomicAdd(&g[(size_t)gi * 1024 + 512 + col], lsum[s][fc][comp]);
    }
  }
}

// ---------------- fc1 (+ fused column stats for bn4) ----------------
__device__ __forceinline__ int lower_bound_i(const int* a, int n, int v) {
  int lo = 0, hi = n;
  while (lo < hi) {
    int mid = (lo + hi) >> 1;
    if (a[mid] < v) lo = mid + 1; else hi = mid;
  }
  return lo;
}

__global__ __launch_bounds__(256) void fc1_kernel(const float* __restrict__ g,
                                                  const int* __restrict__ batch,
                                                  const float* __restrict__ W,
                                                  const float* __restrict__ b,
                                                  float* __restrict__ out,
                                                  float* __restrict__ stats4) {
  __shared__ float sg[1024];
  __shared__ float sred[4][64];
  int gid = blockIdx.x;
  int tid = threadIdx.x;
  int lo = lower_bound_i(batch, N_NODES, gid);
  int hi = lower_bound_i(batch, N_NODES, gid + 1);
  float inv_cnt = 1.0f / fmaxf((float)(hi - lo), 1.0f);
  float4 gv = ((const float4*)(g + (size_t)gid * 1024))[tid];
  if (tid >= 128) {  // mean half: divide sums by count
    gv.x *= inv_cnt; gv.y *= inv_cnt; gv.z *= inv_cnt; gv.w *= inv_cnt;
  }
  ((float4*)sg)[tid] = gv;
  __syncthreads();
  int cl = tid & 63;
  int slice = tid >> 6;
  int col = blockIdx.y * 64 + cl;
  int k0 = slice * 256;
  float acc = 0.f;
#pragma unroll 4
  for (int k = k0; k < k0 + 256; k++) acc += sg[k] * W[(size_t)k * D_H + col];
  sred[slice][cl] = acc;
  __syncthreads();
  if (slice == 0) {
    float v = sred[0][cl] + sred[1][cl] + sred[2][cl] + sred[3][cl] + b[col];
    out[(size_t)gid * D_H + col] = v;
    atomicAdd(&stats4[col], v);
    atomicAdd(&stats4[D_H + col], v * v);
  }
}

// ---------------- fc2 with inline bn4 (stats4) ----------------
__global__ __launch_bounds__(64) void fc2_kernel(const float* __restrict__ y,
                                                 const float* __restrict__ stats4,
                                                 const float* __restrict__ gmm,
                                                 const float* __restrict__ bb,
                                                 const float* __restrict__ W,
                                                 const float* __restrict__ b,
                                                 float* __restrict__ out) {
  int gid = blockIdx.x;
  int lane = threadIdx.x;
  const float invG = 1.0f / (float)N_GRAPHS;
  float a0 = 0.f, a1 = 0.f;
#pragma unroll
  for (int j = 0; j < 8; j++) {
    int k = lane + j * 64;
    float mean = stats4[k] * invG;
    float var = stats4[D_H + k] * invG - mean * mean;
    float sc = rsqrtf(var + BN_EPS) * gmm[k];
    float v = fmaxf(y[(size_t)gid * D_H + k] * sc + bb[k] - mean * sc, 0.f);
    a0 += v * W[k * 2 + 0];
    a1 += v * W[k * 2 + 1];
  }
  for (int off = 32; off; off >>= 1) {
    a0 += __shfl_down(a0, off);
    a1 += __shfl_down(a1, off);
  }
  if (lane == 0) {
    out[gid * 2 + 0] = a0 + b[0];
    out[gid * 2 + 1] = a1 + b[1];
  }
}

extern "C" void kernel_launch(void* const* d_in, const int* in_sizes, int n_in,
                              void* d_out, int out_size, void* d_ws, size_t ws_size,
                              hipStream_t stream) {
  const float* x       = (const float*)d_in[0];
  const float* W0      = (const float*)d_in[1];
  const float* Wrest   = (const float*)d_in[2];
  const float* bconv   = (const float*)d_in[3];
  const float* p       = (const float*)d_in[4];
  const float* mscale  = (const float*)d_in[5];
  const float* bn_g    = (const float*)d_in[6];
  const float* bn_b    = (const float*)d_in[7];
  const float* fc1_W   = (const float*)d_in[8];
  const float* fc1_b   = (const float*)d_in[9];
  const float* bn4_g   = (const float*)d_in[10];
  const float* bn4_b   = (const float*)d_in[11];
  const float* fc2_W   = (const float*)d_in[12];
  const float* fc2_b   = (const float*)d_in[13];
  const int*   eidx    = (const int*)d_in[14];
  const int*   batch   = (const int*)d_in[15];
  float* out = (float*)d_out;

  const int* src = eidx;
  const int* dst = eidx + N_EDGES;

  float* ws = (float*)d_ws;
  const size_t NH = (size_t)N_NODES * D_H;
  float* hlin   = ws;
  float* jk     = hlin + NH;
  float* stats  = jk + NH;            // 3 x 1024
  float* stats4 = stats + 3072;       // 1024
  float* aff    = stats4 + 1024;      // 1024
  __hip_bfloat16* residb = (__hip_bfloat16*)(aff + 1024);   // [M_PAD][512]
  __hip_bfloat16* msgb = residb + (size_t)M_PAD * D_H;      // [N_NODES][512]
  __hip_bfloat16* w0t = msgb + NH;
  __hip_bfloat16* w1t = w0t + 512 * 128;
  __hip_bfloat16* w2t = w1t + 512 * 512;
  int* cnt     = (int*)(w2t + 512 * 512);
  int* rowptr  = cnt + N_NODES;
  int* csr_src = rowptr + N_NODES + 1;
  float* g     = (float*)(csr_src + N_EDGES);   // [64][1024]: max | sum
  float* g2lin = g + 64 * 1024;                 // [64][512]

  // weights + zero {cnt, stats, stats4, g}
  convert_all<<<dim3(16, 16, 3), 256, 0, stream>>>(W0, Wrest, w0t, w1t, w2t,
                                                   cnt, stats, stats4, g);
  // CSR + layer-0 msg table (fused hist+msg0)
  hist_msg0<<<1875, 256, 0, stream>>>(dst, cnt, x, p, msgb);
  scan_kernel<<<1, 256, 0, stream>>>(cnt, rowptr);
  scatter_kernel<<<(N_EDGES + 255) / 256, 256, 0, stream>>>(src, dst, rowptr, cnt, csr_src);

  for (int layer = 0; layer < 3; layer++) {
    if (layer == 0)
      agg_msgnorm_kernel<D_INPUT, false><<<N_NODES, 256, 0, stream>>>(
          x, nullptr, msgb, rowptr, csr_src, p + layer, mscale + layer, residb);
    else
      agg_msgnorm_kernel<D_H, true><<<N_NODES, 256, 0, stream>>>(
          hlin, aff, msgb, rowptr, csr_src, p + layer, mscale + layer, residb);
    const __hip_bfloat16* Wt = (layer == 0) ? w0t : (layer == 1 ? w1t : w2t);
    int K = (layer == 0) ? D_INPUT : D_H;
    float* stats_l = stats + layer * 1024;
    mfma_gemm<<<dim3(M_PAD / 128, D_H / 128), 256, 0, stream>>>(
        residb, Wt, bconv + (size_t)layer * D_H, hlin, stats_l, N_NODES, K);
    if (layer < 2)
      jk_msg_update<<<2048, 256, 0, stream>>>(hlin, stats_l, bn_g + (size_t)layer * D_H,
                                              bn_b + (size_t)layer * D_H, jk,
                                              p + layer + 1, msgb, aff, layer);
    else
      jk_pool_kernel<<<dim3(79, 4), 256, 0, stream>>>(hlin, stats_l,
                                                      bn_g + (size_t)layer * D_H,
                                                      bn_b + (size_t)layer * D_H,
                                                      jk, batch, g);
  }

  fc1_kernel<<<dim3(N_GRAPHS, 8), 256, 0, stream>>>(g, batch, fc1_W, fc1_b, g2lin, stats4);
  fc2_kernel<<<N_GRAPHS, 64, 0, stream>>>(g2lin, stats4, bn4_g, bn4_b, fc2_W, fc2_b, out);
}

// Round 15
// 241.909 us; speedup vs baseline: 1.6684x; 1.0091x over previous
//
#include <hip/hip_runtime.h>
#include <hip/hip_bf16.h>
#include <math.h>

#define N_NODES 10000
#define N_GRAPHS 64
#define N_EDGES 160000
#define D_INPUT 128
#define D_H 512
#define EPS 1e-7f
#define MAXV 10.0f
#define BN_EPS 1e-5f
#define M_PAD 10112  // 79 * 128

typedef __attribute__((ext_vector_type(4))) float f32x4;
typedef __attribute__((ext_vector_type(8))) __bf16 bf16x8;

// ================= fused hist + layer-0 msg table =================
__global__ __launch_bounds__(256) void hist_msg0(const int* __restrict__ dst,
                                                 int* __restrict__ cnt,
                                                 const float* __restrict__ x,
                                                 const float* __restrict__ p_ptr,
                                                 __hip_bfloat16* __restrict__ msgb) {
  int bid = blockIdx.x;
  int tid = threadIdx.x;
  if (bid < 625) {  // 625*256 == N_EDGES
    atomicAdd(&cnt[dst[bid * 256 + tid]], 1);
    return;
  }
  float p = *p_ptr;
  bool p1 = (p == 1.0f);
  const int total = N_NODES * D_INPUT / 2;
  for (int i = (bid - 625) * 256 + tid; i < total; i += 320000) {
    float2 v = ((const float2*)x)[i];
    float m0 = fminf(fmaxf(v.x, 0.f) + EPS, MAXV);
    float m1 = fminf(fmaxf(v.y, 0.f) + EPS, MAXV);
    if (!p1) { m0 = powf(m0, p); m1 = powf(m1, p); }
    __hip_bfloat162 o;
    o.x = __float2bfloat16(m0);
    o.y = __float2bfloat16(m1);
    ((__hip_bfloat162*)msgb)[i] = o;
  }
}

// single-block scan; reads cnt via int4, writes rowptr via int4, zeroes cnt
__global__ __launch_bounds__(256) void scan_kernel(int* __restrict__ cnt,
                                                   int* __restrict__ rowptr) {
  __shared__ int ps[256];
  int tid = threadIdx.x;
  const int CH = 40;
  int b0 = tid * CH;
  bool active = (b0 < N_NODES);
  int v[CH];
  int s = 0;
  if (active) {
    const int4* c4p = (const int4*)(cnt + b0);
#pragma unroll
    for (int i = 0; i < CH / 4; i++) {
      int4 q = c4p[i];
      v[4 * i] = q.x; v[4 * i + 1] = q.y; v[4 * i + 2] = q.z; v[4 * i + 3] = q.w;
      s += q.x + q.y + q.z + q.w;
    }
  }
  ps[tid] = s;
  __syncthreads();
  for (int off = 1; off < 256; off <<= 1) {
    int t = (tid >= off) ? ps[tid - off] : 0;
    __syncthreads();
    ps[tid] += t;
    __syncthreads();
  }
  int run = (tid == 0) ? 0 : ps[tid - 1];
  if (active) {
    int r[CH];
#pragma unroll
    for (int i = 0; i < CH; i++) { r[i] = run; run += v[i]; }
    int4* rp = (int4*)(rowptr + b0);
    int4* cz = (int4*)(cnt + b0);
#pragma unroll
    for (int i = 0; i < CH / 4; i++) {
      rp[i] = make_int4(r[4 * i], r[4 * i + 1], r[4 * i + 2], r[4 * i + 3]);
      cz[i] = make_int4(0, 0, 0, 0);
    }
  }
  if (tid == 255) rowptr[N_NODES] = ps[255];
}

__global__ __launch_bounds__(256) void scatter_kernel(
    const int* __restrict__ src, const int* __restrict__ dst,
    const int* __restrict__ rowptr, int* __restrict__ cursor,
    int* __restrict__ csr_src) {
  int i = blockIdx.x * blockDim.x + threadIdx.x;
  if (i < N_EDGES) {
    int t = dst[i];
    int pos = rowptr[t] + atomicAdd(&cursor[t], 1);
    csr_src[pos] = src[i];
  }
}

// ============ fused: CSR aggregation (bf16 msg table, 4B gather, 8-deep MLP)
//              + power-mean + MessageNorm + residual (bf16 out) ============
template <int D, bool BN>
__global__ __launch_bounds__(256) void agg_msgnorm_kernel(
    const float* __restrict__ h, const float* __restrict__ aff,
    const __hip_bfloat16* __restrict__ msgb,
    const int* __restrict__ rowptr, const int* __restrict__ csr_src,
    const float* __restrict__ p_ptr, const float* __restrict__ scale_ptr,
    __hip_bfloat16* __restrict__ out) {
  constexpr int C = D / 2;
  constexpr int SL = 256 / C;
  int n = blockIdx.x;
  int tid = threadIdx.x;
  int col = tid % C;
  int slice = tid / C;
  int lo = rowptr[n], hi = rowptr[n + 1];
  float p = *p_ptr;
  float scale = *scale_ptr;
  bool p1 = (p == 1.0f);
  float invp = 1.0f / p;
  float inv_dg = 1.0f / fmaxf((float)(hi - lo), 1.0f);
  const float2* h2 = (const float2*)h;
  const uint* mg = (const uint*)msgb;

  __shared__ int s_src[256];  // pre-multiplied row offsets (src * C)
  float accx = 0.f, accy = 0.f;
  for (int base = lo; base < hi; base += 256) {
    int m = min(256, hi - base);
    __syncthreads();
    if (tid < m) s_src[tid] = csr_src[base + tid] * C;
    __syncthreads();
    int j = slice;
    // 8 independent loads in flight per thread (latency-bound gather)
    for (; j + 7 * SL < m; j += 8 * SL) {
      uint u0 = mg[s_src[j] + col];
      uint u1 = mg[s_src[j + SL] + col];
      uint u2 = mg[s_src[j + 2 * SL] + col];
      uint u3 = mg[s_src[j + 3 * SL] + col];
      uint u4 = mg[s_src[j + 4 * SL] + col];
      uint u5 = mg[s_src[j + 5 * SL] + col];
      uint u6 = mg[s_src[j + 6 * SL] + col];
      uint u7 = mg[s_src[j + 7 * SL] + col];
      accx += ((__uint_as_float(u0 << 16) + __uint_as_float(u1 << 16)) +
               (__uint_as_float(u2 << 16) + __uint_as_float(u3 << 16))) +
              ((__uint_as_float(u4 << 16) + __uint_as_float(u5 << 16)) +
               (__uint_as_float(u6 << 16) + __uint_as_float(u7 << 16)));
      accy += ((__uint_as_float(u0 & 0xFFFF0000u) + __uint_as_float(u1 & 0xFFFF0000u)) +
               (__uint_as_float(u2 & 0xFFFF0000u) + __uint_as_float(u3 & 0xFFFF0000u))) +
              ((__uint_as_float(u4 & 0xFFFF0000u) + __uint_as_float(u5 & 0xFFFF0000u)) +
               (__uint_as_float(u6 & 0xFFFF0000u) + __uint_as_float(u7 & 0xFFFF0000u)));
    }
    for (; j + 3 * SL < m; j += 4 * SL) {
      uint u0 = mg[s_src[j] + col];
      uint u1 = mg[s_src[j + SL] + col];
      uint u2 = mg[s_src[j + 2 * SL] + col];
      uint u3 = mg[s_src[j + 3 * SL] + col];
      accx += (__uint_as_float(u0 << 16) + __uint_as_float(u1 << 16)) +
              (__uint_as_float(u2 << 16) + __uint_as_float(u3 << 16));
      accy += (__uint_as_float(u0 & 0xFFFF0000u) + __uint_as_float(u1 & 0xFFFF0000u)) +
              (__uint_as_float(u2 & 0xFFFF0000u) + __uint_as_float(u3 & 0xFFFF0000u));
    }
    for (; j < m; j += SL) {
      uint u = mg[s_src[j] + col];
      accx += __uint_as_float(u << 16);
      accy += __uint_as_float(u & 0xFFFF0000u);
    }
  }

  if constexpr (SL > 1) {
    __shared__ float sacc[2][256];
    sacc[0][tid] = accx;
    sacc[1][tid] = accy;
    __syncthreads();
    if (tid < C) {
#pragma unroll
      for (int s = 1; s < SL; s++) {
        accx += sacc[0][s * C + tid];
        accy += sacc[1][s * C + tid];
      }
    }
  }

  float a0 = 0.f, a1 = 0.f, hv0 = 0.f, hv1 = 0.f, sa = 0.f, sh = 0.f;
  if (tid < C) {
    a0 = fminf(fmaxf(accx * inv_dg, EPS), MAXV);
    a1 = fminf(fmaxf(accy * inv_dg, EPS), MAXV);
    if (!p1) { a0 = powf(a0, invp); a1 = powf(a1, invp); }
    float2 hx = h2[(size_t)n * C + tid];
    if constexpr (BN) {
      float2 s2 = ((const float2*)aff)[tid];
      float2 b2 = ((const float2*)(aff + D_H))[tid];
      hx.x = fmaxf(hx.x * s2.x + b2.x, 0.f);
      hx.y = fmaxf(hx.y * s2.y + b2.y, 0.f);
    }
    hv0 = hx.x;
    hv1 = hx.y;
    sa = a0 * a0 + a1 * a1;
    sh = hv0 * hv0 + hv1 * hv1;
  }
  for (int off = 32; off; off >>= 1) {
    sa += __shfl_down(sa, off);
    sh += __shfl_down(sh, off);
  }
  __shared__ float red[2][4];
  __shared__ float tot[2];
  int wid = tid >> 6;
  if ((tid & 63) == 0) { red[0][wid] = sa; red[1][wid] = sh; }
  __syncthreads();
  if (tid == 0) {
    tot[0] = red[0][0] + red[0][1] + red[0][2] + red[0][3];
    tot[1] = red[1][0] + red[1][1] + red[1][2] + red[1][3];
  }
  __syncthreads();
  float k = sqrtf(tot[1]) * scale / fmaxf(sqrtf(tot[0]), 1e-12f);
  if (tid < C) {
    __hip_bfloat162 o2;
    o2.x = __float2bfloat16(hv0 + a0 * k);
    o2.y = __float2bfloat16(hv1 + a1 * k);
    ((__hip_bfloat162*)out)[(size_t)n * C + tid] = o2;
  }
}

// ============ weight convert+transpose (3 mats) + zero {cnt, stats x3, stats4, g} ============
__global__ __launch_bounds__(256) void convert_all(
    const float* __restrict__ W0, const float* __restrict__ Wrest,
    __hip_bfloat16* __restrict__ w0t, __hip_bfloat16* __restrict__ w1t,
    __hip_bfloat16* __restrict__ w2t, int* __restrict__ cnt,
    float* __restrict__ stats, float* __restrict__ stats4,
    float* __restrict__ g) {
  int z = blockIdx.z;
  const float* W;
  __hip_bfloat16* Wt;
  int K;
  if (z == 0) { W = W0; Wt = w0t; K = D_INPUT; }
  else if (z == 1) { W = Wrest; Wt = w1t; K = D_H; }
  else { W = Wrest + (size_t)D_H * D_H; Wt = w2t; K = D_H; }

  if (z == 0 && blockIdx.x >= 4) {
    // spare: zero cnt[10000] + stats[3072] + stats4[1024] + g[65536]
    int base = ((blockIdx.x - 4) * 16 + blockIdx.y) * 256 + threadIdx.x;  // 0..49151
    const int TOT = 10000 + 3072 + 1024 + 65536;                          // 79632
    for (int e = base; e < TOT; e += 49152) {
      if (e < 10000) cnt[e] = 0;
      else {
        int f = e - 10000;
        if (f < 3072) stats[f] = 0.f;
        else if (f < 4096) stats4[f - 3072] = 0.f;
        else g[f - 4096] = 0.f;
      }
    }
    return;
  }

  __shared__ float tile[32][33];
  int k0 = blockIdx.x * 32, n0 = blockIdx.y * 32;
  int tx = threadIdx.x & 31, ty = threadIdx.x >> 5;
  for (int i = ty; i < 32; i += 8)
    tile[i][tx] = W[(size_t)(k0 + i) * D_H + n0 + tx];
  __syncthreads();
  for (int i = ty; i < 32; i += 8)
    Wt[(size_t)(n0 + i) * K + k0 + tx] = __float2bfloat16(tile[tx][i]);
}

// ============ MFMA bf16 GEMM + fused column stats ============
__global__ __launch_bounds__(256) void mfma_gemm(
    const __hip_bfloat16* __restrict__ A, const __hip_bfloat16* __restrict__ Bt,
    const float* __restrict__ bias, float* __restrict__ C, float* __restrict__ stats,
    int M, int K) {
  __shared__ ushort As[128 * 64];
  __shared__ ushort Bs[128 * 64];
  __shared__ float sred[128][2];
  int tid = threadIdx.x;
  int l = tid & 63;
  int w = tid >> 6;
  int wm = w >> 1, wn = w & 1;
  int row0 = blockIdx.x * 128;
  int col0 = blockIdx.y * 128;

  f32x4 acc[4][4];
#pragma unroll
  for (int m = 0; m < 4; m++)
#pragma unroll
    for (int n = 0; n < 4; n++) acc[m][n] = (f32x4){0.f, 0.f, 0.f, 0.f};

  const ushort* Ag = (const ushort*)A;
  const ushort* Bg = (const ushort*)Bt;
  char* AsB = (char*)As;
  char* BsB = (char*)Bs;

  if (tid < 128) { sred[tid][0] = 0.f; sred[tid][1] = 0.f; }

  int srow = tid >> 3;
  int scb = (tid & 7) * 16;
  int wbyte = scb ^ ((srow & 7) << 4);
  int scol = scb >> 1;

  int lswz = (l & 7) << 4;
  int kb = (l >> 4) * 16;
  int arow = wm * 64 + (l & 15);
  int brow = wn * 64 + (l & 15);

  for (int k0 = 0; k0 < K; k0 += 64) {
    uint4 ra[4], rb[4];
#pragma unroll
    for (int j = 0; j < 4; j++) {
      int row = j * 32 + srow;
      ra[j] = *(const uint4*)(Ag + (size_t)(row0 + row) * K + k0 + scol);
      rb[j] = *(const uint4*)(Bg + (size_t)(col0 + row) * K + k0 + scol);
    }
#pragma unroll
    for (int j = 0; j < 4; j++) {
      int row = j * 32 + srow;
      *(uint4*)(AsB + row * 128 + wbyte) = ra[j];
      *(uint4*)(BsB + row * 128 + wbyte) = rb[j];
    }
    __syncthreads();
#pragma unroll
    for (int kk = 0; kk < 2; kk++) {
      bf16x8 af[4], bfr[4];
#pragma unroll
      for (int m = 0; m < 4; m++)
        af[m] = *(const bf16x8*)(AsB + (arow + m * 16) * 128 + ((kk * 64 + kb) ^ lswz));
#pragma unroll
      for (int n = 0; n < 4; n++)
        bfr[n] = *(const bf16x8*)(BsB + (brow + n * 16) * 128 + ((kk * 64 + kb) ^ lswz));
#pragma unroll
      for (int m = 0; m < 4; m++)
#pragma unroll
        for (int n = 0; n < 4; n++)
          acc[m][n] = __builtin_amdgcn_mfma_f32_16x16x32_bf16(af[m], bfr[n], acc[m][n], 0, 0, 0);
    }
    __syncthreads();
  }

  int crow0 = row0 + wm * 64 + (l >> 4) * 4;
  int ccol0 = col0 + wn * 64 + (l & 15);
#pragma unroll
  for (int n = 0; n < 4; n++) {
    int col = ccol0 + n * 16;
    float bv = bias[col];
    float ps = 0.f, pq = 0.f;
#pragma unroll
    for (int m = 0; m < 4; m++) {
#pragma unroll
      for (int r = 0; r < 4; r++) {
        int rr = crow0 + m * 16 + r;
        if (rr < M) {
          float v = acc[m][n][r] + bv;
          C[(size_t)rr * D_H + col] = v;
          ps += v;
          pq += v * v;
        }
      }
    }
    ps += __shfl_down(ps, 16); pq += __shfl_down(pq, 16);
    ps += __shfl_down(ps, 32); pq += __shfl_down(pq, 32);
    if ((l >> 4) == 0) {
      atomicAdd(&sred[wn * 64 + n * 16 + (l & 15)][0], ps);
      atomicAdd(&sred[wn * 64 + n * 16 + (l & 15)][1], pq);
    }
  }
  __syncthreads();
  if (tid < 128) {
    atomicAdd(&stats[col0 + tid], sred[tid][0]);
    atomicAdd(&stats[D_H + col0 + tid], sred[tid][1]);
  }
}

// ---------------- JK update + next-layer msg table; BN-affine computed inline
//                  from stats; block 0 publishes aff for the next agg ----------------
__global__ __launch_bounds__(256) void jk_msg_update(
    const float* __restrict__ hlin, const float* __restrict__ stats,
    const float* __restrict__ gamma, const float* __restrict__ beta,
    float* __restrict__ jk, const float* __restrict__ p_ptr,
    __hip_bfloat16* __restrict__ msgb, float* __restrict__ aff, int layer) {
  float p = *p_ptr;
  bool p1 = (p == 1.0f);
  const float invN = 1.0f / (float)N_NODES;
  const int total = N_NODES * D_H / 4;
  for (int idx = blockIdx.x * blockDim.x + threadIdx.x; idx < total;
       idx += gridDim.x * blockDim.x) {
    int c4 = idx & 127;
    float4 s4 = ((const float4*)stats)[c4];
    float4 q4 = ((const float4*)(stats + D_H))[c4];
    float4 g4 = ((const float4*)gamma)[c4];
    float4 b4 = ((const float4*)beta)[c4];
    float4 sc, sh;
    {
      float m0 = s4.x * invN, m1 = s4.y * invN, m2 = s4.z * invN, m3 = s4.w * invN;
      sc.x = rsqrtf(q4.x * invN - m0 * m0 + BN_EPS) * g4.x;
      sc.y = rsqrtf(q4.y * invN - m1 * m1 + BN_EPS) * g4.y;
      sc.z = rsqrtf(q4.z * invN - m2 * m2 + BN_EPS) * g4.z;
      sc.w = rsqrtf(q4.w * invN - m3 * m3 + BN_EPS) * g4.w;
      sh.x = b4.x - m0 * sc.x;
      sh.y = b4.y - m1 * sc.y;
      sh.z = b4.z - m2 * sc.z;
      sh.w = b4.w - m3 * sc.w;
    }
    if (idx < 128) {  // block 0, first pass: publish aff
      ((float4*)aff)[idx] = sc;
      ((float4*)(aff + D_H))[idx] = sh;
    }
    float4 x = ((const float4*)hlin)[idx];
    float4 v;
    v.x = fmaxf(x.x * sc.x + sh.x, 0.f);
    v.y = fmaxf(x.y * sc.y + sh.y, 0.f);
    v.z = fmaxf(x.z * sc.z + sh.z, 0.f);
    v.w = fmaxf(x.w * sc.w + sh.w, 0.f);
    {
      float m0 = fminf(v.x + EPS, MAXV);
      float m1 = fminf(v.y + EPS, MAXV);
      float m2 = fminf(v.z + EPS, MAXV);
      float m3 = fminf(v.w + EPS, MAXV);
      if (!p1) { m0 = powf(m0, p); m1 = powf(m1, p); m2 = powf(m2, p); m3 = powf(m3, p); }
      __hip_bfloat162 o01, o23;
      o01.x = __float2bfloat16(m0); o01.y = __float2bfloat16(m1);
      o23.x = __float2bfloat16(m2); o23.y = __float2bfloat16(m3);
      ((__hip_bfloat162*)msgb)[2 * idx] = o01;
      ((__hip_bfloat162*)msgb)[2 * idx + 1] = o23;
    }
    if (layer != 0) {
      float4 j = ((const float4*)jk)[idx];
      v.x = fmaxf(v.x, j.x);
      v.y = fmaxf(v.y, j.y);
      v.z = fmaxf(v.z, j.z);
      v.w = fmaxf(v.w, j.w);
    }
    ((float4*)jk)[idx] = v;
  }
}

// ---------------- layer-2: BN inline + jk-max + fused per-graph pooling ----------------
__global__ __launch_bounds__(256) void jk_pool_kernel(
    const float* __restrict__ hlin, const float* __restrict__ stats,
    const float* __restrict__ gamma, const float* __restrict__ beta,
    const float* __restrict__ jk, const int* __restrict__ batch,
    float* __restrict__ g) {
  int tid = threadIdx.x;
  int f4l = tid & 31;
  int rs = tid >> 5;
  int row0 = blockIdx.x * 128;
  int c4 = blockIdx.y * 32 + f4l;

  __shared__ int s_batch[128];
  __shared__ int lmax[4][32][4];
  __shared__ float lsum[4][32][4];
  if (tid < 128) {
    int r = row0 + tid;
    s_batch[tid] = (r < N_NODES) ? batch[r] : -1;
  }
  for (int i = tid; i < 512; i += 256) {
    ((int*)lmax)[i] = 0;
    ((float*)lsum)[i] = 0.f;
  }
  __syncthreads();
  int g_first = s_batch[0];

  const float invN = 1.0f / (float)N_NODES;
  float4 s4 = ((const float4*)stats)[c4];
  float4 q4 = ((const float4*)(stats + D_H))[c4];
  float4 g4 = ((const float4*)gamma)[c4];
  float4 b4 = ((const float4*)beta)[c4];
  float4 sc, sh;
  {
    float m0 = s4.x * invN, m1 = s4.y * invN, m2 = s4.z * invN, m3 = s4.w * invN;
    sc.x = rsqrtf(q4.x * invN - m0 * m0 + BN_EPS) * g4.x;
    sc.y = rsqrtf(q4.y * invN - m1 * m1 + BN_EPS) * g4.y;
    sc.z = rsqrtf(q4.z * invN - m2 * m2 + BN_EPS) * g4.z;
    sc.w = rsqrtf(q4.w * invN - m3 * m3 + BN_EPS) * g4.w;
    sh.x = b4.x - m0 * sc.x;
    sh.y = b4.y - m1 * sc.y;
    sh.z = b4.z - m2 * sc.z;
    sh.w = b4.w - m3 * sc.w;
  }

  float4 mx = make_float4(0.f, 0.f, 0.f, 0.f);
  float4 sm = make_float4(0.f, 0.f, 0.f, 0.f);
  int cur = -1;

#define FLUSH()                                                              \
  do {                                                                       \
    int slot = cur - g_first;                                                \
    if (slot < 4) {                                                          \
      atomicMax(&lmax[slot][f4l][0], __float_as_int(mx.x));                  \
      atomicMax(&lmax[slot][f4l][1], __float_as_int(mx.y));                  \
      atomicMax(&lmax[slot][f4l][2], __float_as_int(mx.z));                  \
      atomicMax(&lmax[slot][f4l][3], __float_as_int(mx.w));                  \
      atomicAdd(&lsum[slot][f4l][0], sm.x);                                  \
      atomicAdd(&lsum[slot][f4l][1], sm.y);                                  \
      atomicAdd(&lsum[slot][f4l][2], sm.z);                                  \
      atomicAdd(&lsum[slot][f4l][3], sm.w);                                  \
    } else {                                                                 \
      int cb = c4 * 4;                                                       \
      atomicMax((int*)&g[(size_t)cur * 1024 + cb + 0], __float_as_int(mx.x)); \
      atomicMax((int*)&g[(size_t)cur * 1024 + cb + 1], __float_as_int(mx.y)); \
      atomicMax((int*)&g[(size_t)cur * 1024 + cb + 2], __float_as_int(mx.z)); \
      atomicMax((int*)&g[(size_t)cur * 1024 + cb + 3], __float_as_int(mx.w)); \
      atomicAdd(&g[(size_t)cur * 1024 + 512 + cb + 0], sm.x);                \
      atomicAdd(&g[(size_t)cur * 1024 + 512 + cb + 1], sm.y);                \
      atomicAdd(&g[(size_t)cur * 1024 + 512 + cb + 2], sm.z);                \
      atomicAdd(&g[(size_t)cur * 1024 + 512 + cb + 3], sm.w);                \
    }                                                                        \
  } while (0)

  for (int i = 0; i < 16; i++) {
    int r = row0 + rs + i * 8;
    if (r >= N_NODES) break;
    int gg = s_batch[rs + i * 8];
    if (gg != cur) {
      if (cur >= 0) FLUSH();
      cur = gg;
      mx = make_float4(0.f, 0.f, 0.f, 0.f);
      sm = make_float4(0.f, 0.f, 0.f, 0.f);
    }
    float4 x = ((const float4*)hlin)[(size_t)r * 128 + c4];
    float4 j4 = ((const float4*)jk)[(size_t)r * 128 + c4];
    float4 v;
    v.x = fmaxf(fmaxf(x.x * sc.x + sh.x, 0.f), j4.x);
    v.y = fmaxf(fmaxf(x.y * sc.y + sh.y, 0.f), j4.y);
    v.z = fmaxf(fmaxf(x.z * sc.z + sh.z, 0.f), j4.z);
    v.w = fmaxf(fmaxf(x.w * sc.w + sh.w, 0.f), j4.w);
    mx.x = fmaxf(mx.x, v.x); mx.y = fmaxf(mx.y, v.y);
    mx.z = fmaxf(mx.z, v.z); mx.w = fmaxf(mx.w, v.w);
    sm.x += v.x; sm.y += v.y; sm.z += v.z; sm.w += v.w;
  }
  if (cur >= 0) FLUSH();
#undef FLUSH
  __syncthreads();

  int last = min(127, N_NODES - 1 - row0);
  int g_last = s_batch[last];
  int ns = min(3, g_last - g_first);
  for (int s = 0; s <= ns; s++) {
    int gi = g_first + s;
    if (tid < 128) {
      int fc = tid >> 2, comp = tid & 3;
      int col = (blockIdx.y * 32 + fc) * 4 + comp;
      atomicMax((int*)&g[(size_t)gi * 1024 + col], lmax[s][fc][comp]);
    } else {
      int t = tid - 128;
      int fc = t >> 2, comp = t & 3;
      int col = (blockIdx.y * 32 + fc) * 4 + comp;
      atomicAdd(&g[(size_t)gi * 1024 + 512 + col], lsum[s][fc][comp]);
    }
  }
}

// ---------------- fc1 (+ fused column stats for bn4) ----------------
__device__ __forceinline__ int lower_bound_i(const int* a, int n, int v) {
  int lo = 0, hi = n;
  while (lo < hi) {
    int mid = (lo + hi) >> 1;
    if (a[mid] < v) lo = mid + 1; else hi = mid;
  }
  return lo;
}

__global__ __launch_bounds__(256) void fc1_kernel(const float* __restrict__ g,
                                                  const int* __restrict__ batch,
                                                  const float* __restrict__ W,
                                                  const float* __restrict__ b,
                                                  float* __restrict__ out,
                                                  float* __restrict__ stats4) {
  __shared__ float sg[1024];
  __shared__ float sred[4][64];
  int gid = blockIdx.x;
  int tid = threadIdx.x;
  int lo = lower_bound_i(batch, N_NODES, gid);
  int hi = lower_bound_i(batch, N_NODES, gid + 1);
  float inv_cnt = 1.0f / fmaxf((float)(hi - lo), 1.0f);
  float4 gv = ((const float4*)(g + (size_t)gid * 1024))[tid];
  if (tid >= 128) {  // mean half: divide sums by count
    gv.x *= inv_cnt; gv.y *= inv_cnt; gv.z *= inv_cnt; gv.w *= inv_cnt;
  }
  ((float4*)sg)[tid] = gv;
  __syncthreads();
  int cl = tid & 63;
  int slice = tid >> 6;
  int col = blockIdx.y * 64 + cl;
  int k0 = slice * 256;
  float acc = 0.f;
#pragma unroll 4
  for (int k = k0; k < k0 + 256; k++) acc += sg[k] * W[(size_t)k * D_H + col];
  sred[slice][cl] = acc;
  __syncthreads();
  if (slice == 0) {
    float v = sred[0][cl] + sred[1][cl] + sred[2][cl] + sred[3][cl] + b[col];
    out[(size_t)gid * D_H + col] = v;
    atomicAdd(&stats4[col], v);
    atomicAdd(&stats4[D_H + col], v * v);
  }
}

// ---------------- fc2 with inline bn4 (stats4) ----------------
__global__ __launch_bounds__(64) void fc2_kernel(const float* __restrict__ y,
                                                 const float* __restrict__ stats4,
                                                 const float* __restrict__ gmm,
                                                 const float* __restrict__ bb,
                                                 const float* __restrict__ W,
                                                 const float* __restrict__ b,
                                                 float* __restrict__ out) {
  int gid = blockIdx.x;
  int lane = threadIdx.x;
  const float invG = 1.0f / (float)N_GRAPHS;
  float a0 = 0.f, a1 = 0.f;
#pragma unroll
  for (int j = 0; j < 8; j++) {
    int k = lane + j * 64;
    float mean = stats4[k] * invG;
    float var = stats4[D_H + k] * invG - mean * mean;
    float sc = rsqrtf(var + BN_EPS) * gmm[k];
    float v = fmaxf(y[(size_t)gid * D_H + k] * sc + bb[k] - mean * sc, 0.f);
    a0 += v * W[k * 2 + 0];
    a1 += v * W[k * 2 + 1];
  }
  for (int off = 32; off; off >>= 1) {
    a0 += __shfl_down(a0, off);
    a1 += __shfl_down(a1, off);
  }
  if (lane == 0) {
    out[gid * 2 + 0] = a0 + b[0];
    out[gid * 2 + 1] = a1 + b[1];
  }
}

extern "C" void kernel_launch(void* const* d_in, const int* in_sizes, int n_in,
                              void* d_out, int out_size, void* d_ws, size_t ws_size,
                              hipStream_t stream) {
  const float* x       = (const float*)d_in[0];
  const float* W0      = (const float*)d_in[1];
  const float* Wrest   = (const float*)d_in[2];
  const float* bconv   = (const float*)d_in[3];
  const float* p       = (const float*)d_in[4];
  const float* mscale  = (const float*)d_in[5];
  const float* bn_g    = (const float*)d_in[6];
  const float* bn_b    = (const float*)d_in[7];
  const float* fc1_W   = (const float*)d_in[8];
  const float* fc1_b   = (const float*)d_in[9];
  const float* bn4_g   = (const float*)d_in[10];
  const float* bn4_b   = (const float*)d_in[11];
  const float* fc2_W   = (const float*)d_in[12];
  const float* fc2_b   = (const float*)d_in[13];
  const int*   eidx    = (const int*)d_in[14];
  const int*   batch   = (const int*)d_in[15];
  float* out = (float*)d_out;

  const int* src = eidx;
  const int* dst = eidx + N_EDGES;

  float* ws = (float*)d_ws;
  const size_t NH = (size_t)N_NODES * D_H;
  float* hlin   = ws;
  float* jk     = hlin + NH;
  float* stats  = jk + NH;            // 3 x 1024
  float* stats4 = stats + 3072;       // 1024
  float* aff    = stats4 + 1024;      // 1024
  __hip_bfloat16* residb = (__hip_bfloat16*)(aff + 1024);   // [M_PAD][512]
  __hip_bfloat16* msgb = residb + (size_t)M_PAD * D_H;      // [N_NODES][512]
  __hip_bfloat16* w0t = msgb + NH;
  __hip_bfloat16* w1t = w0t + 512 * 128;
  __hip_bfloat16* w2t = w1t + 512 * 512;
  int* cnt     = (int*)(w2t + 512 * 512);
  int* rowptr  = cnt + N_NODES;
  int* csr_src = rowptr + N_NODES + 1;
  float* g     = (float*)(csr_src + N_EDGES);   // [64][1024]: max | sum
  float* g2lin = g + 64 * 1024;                 // [64][512]

  // weights + zero {cnt, stats, stats4, g}
  convert_all<<<dim3(16, 16, 3), 256, 0, stream>>>(W0, Wrest, w0t, w1t, w2t,
                                                   cnt, stats, stats4, g);
  // CSR + layer-0 msg table (fused hist+msg0)
  hist_msg0<<<1875, 256, 0, stream>>>(dst, cnt, x, p, msgb);
  scan_kernel<<<1, 256, 0, stream>>>(cnt, rowptr);
  scatter_kernel<<<(N_EDGES + 255) / 256, 256, 0, stream>>>(src, dst, rowptr, cnt, csr_src);

  for (int layer = 0; layer < 3; layer++) {
    if (layer == 0)
      agg_msgnorm_kernel<D_INPUT, false><<<N_NODES, 256, 0, stream>>>(
          x, nullptr, msgb, rowptr, csr_src, p + layer, mscale + layer, residb);
    else
      agg_msgnorm_kernel<D_H, true><<<N_NODES, 256, 0, stream>>>(
          hlin, aff, msgb, rowptr, csr_src, p + layer, mscale + layer, residb);
    const __hip_bfloat16* Wt = (layer == 0) ? w0t : (layer == 1 ? w1t : w2t);
    int K = (layer == 0) ? D_INPUT : D_H;
    float* stats_l = stats + layer * 1024;
    mfma_gemm<<<dim3(M_PAD / 128, D_H / 128), 256, 0, stream>>>(
        residb, Wt, bconv + (size_t)layer * D_H, hlin, stats_l, N_NODES, K);
    if (layer < 2)
      jk_msg_update<<<2048, 256, 0, stream>>>(hlin, stats_l, bn_g + (size_t)layer * D_H,
                                              bn_b + (size_t)layer * D_H, jk,
                                              p + layer + 1, msgb, aff, layer);
    else
      jk_pool_kernel<<<dim3(79, 4), 256, 0, stream>>>(hlin, stats_l,
                                                      bn_g + (size_t)layer * D_H,
                                                      bn_b + (size_t)layer * D_H,
                                                      jk, batch, g);
  }

  fc1_kernel<<<dim3(N_GRAPHS, 8), 256, 0, stream>>>(g, batch, fc1_W, fc1_b, g2lin, stats4);
  fc2_kernel<<<N_GRAPHS, 64, 0, stream>>>(g2lin, stats4, bn4_g, bn4_b, fc2_W, fc2_b, out);
}